// Round 1
// baseline (923.362 us; speedup 1.0000x reference)
//
#include <hip/hip_runtime.h>

#define NN 50000
#define NE 800000
#define C 64
#define NL 4

// ---------------- degree ----------------
__global__ void deg_kernel(const int* __restrict__ dst, float* __restrict__ deg) {
    int i = blockIdx.x * blockDim.x + threadIdx.x;
    int stride = gridDim.x * blockDim.x;
    for (int e = i; e < NE; e += stride)
        atomicAdd(&deg[dst[e]], 1.0f);
}

__global__ void deg_inv_kernel(float* __restrict__ deg) {
    int i = blockIdx.x * blockDim.x + threadIdx.x;
    if (i < NN) deg[i] = 1.0f / fmaxf(deg[i], 1.0f);
}

// ---------------- edge scatter: agg[dst] += x[src] ----------------
// one wave per edge; lane = channel. Coalesced 256B gather + 64 coalesced atomics.
__global__ void scatter_kernel(const float* __restrict__ x, const int* __restrict__ src,
                               const int* __restrict__ dst, float* __restrict__ agg) {
    int lane = threadIdx.x & 63;
    int wave = (blockIdx.x * blockDim.x + threadIdx.x) >> 6;
    int nwaves = (gridDim.x * blockDim.x) >> 6;
    for (int e = wave; e < NE; e += nwaves) {
        int s = src[e];
        int d = dst[e];
        float v = x[s * C + lane];
        atomicAdd(&agg[d * C + lane], v);
    }
}

// ---------------- node update: out = prelu((agg*deginv)@Wl + x@Wr + b) ----------------
// 16 nodes per block, 256 threads; Wl/Wr staged in LDS (32KB), x/agg tiles in LDS.
__global__ __launch_bounds__(256) void node_kernel(
    const float* __restrict__ xin, const float* __restrict__ agg,
    const float* __restrict__ deginv,
    const float* __restrict__ Wl, const float* __restrict__ Wr,
    const float* __restrict__ bias, const float* __restrict__ alpha,
    float* __restrict__ xout)
{
    __shared__ float wl[C * C];
    __shared__ float wr[C * C];
    __shared__ float xs[16][C];
    __shared__ float as[16][C];
    __shared__ float bs[C];
    __shared__ float als[C];

    int tid = threadIdx.x;
    for (int i = tid; i < C * C; i += 256) {
        wl[i] = Wl[i];
        wr[i] = Wr[i];
    }
    if (tid < C) {
        bs[tid] = bias[tid];
        als[tid] = alpha[tid];
    }

    int node0 = blockIdx.x * 16;  // NN = 50000 = 3125 * 16, exact
    for (int i = tid; i < 16 * C; i += 256) {
        int nl = i >> 6;
        int k = i & 63;
        int n = node0 + nl;
        xs[nl][k] = xin[n * C + k];
        as[nl][k] = agg[n * C + k] * deginv[n];
    }
    __syncthreads();

    int c = tid & 63;
    int g = tid >> 6;  // 0..3
    #pragma unroll
    for (int rep = 0; rep < 4; rep++) {
        int nl = g * 4 + rep;
        float acc = bs[c];
        #pragma unroll
        for (int k = 0; k < C; k++) {
            acc += as[nl][k] * wl[k * C + c] + xs[nl][k] * wr[k * C + c];
        }
        float out = acc >= 0.f ? acc : als[c] * acc;
        xout[(node0 + nl) * C + c] = out;
    }
}

extern "C" void kernel_launch(void* const* d_in, const int* in_sizes, int n_in,
                              void* d_out, int out_size, void* d_ws, size_t ws_size,
                              hipStream_t stream) {
    const float* x     = (const float*)d_in[0];
    const int*   ei    = (const int*)d_in[1];
    const float* Wl    = (const float*)d_in[2];
    const float* Wr    = (const float*)d_in[3];
    const float* b     = (const float*)d_in[4];
    const float* alpha = (const float*)d_in[5];
    float* out = (float*)d_out;

    const int* src = ei;        // edge_index[0]
    const int* dst = ei + NE;   // edge_index[1]

    float* ws  = (float*)d_ws;
    float* deg = ws;                 // NN
    float* agg = ws + NN;            // NN*C
    float* x0  = agg + (size_t)NN * C;
    float* x1  = x0 + (size_t)NN * C;

    // degrees (recomputed every call; deterministic)
    hipMemsetAsync(deg, 0, NN * sizeof(float), stream);
    deg_kernel<<<2048, 256, 0, stream>>>(dst, deg);
    deg_inv_kernel<<<(NN + 255) / 256, 256, 0, stream>>>(deg);

    const float* cur = x;
    for (int l = 0; l < NL; l++) {
        hipMemsetAsync(agg, 0, (size_t)NN * C * sizeof(float), stream);
        scatter_kernel<<<2048, 256, 0, stream>>>(cur, src, dst, agg);
        float* dest = (l == NL - 1) ? out : ((l & 1) ? x1 : x0);
        node_kernel<<<3125, 256, 0, stream>>>(cur, agg, deg,
                                              Wl + (size_t)l * C * C,
                                              Wr + (size_t)l * C * C,
                                              b + (size_t)l * C,
                                              alpha + (size_t)l * C,
                                              dest);
        cur = dest;
    }
}